// Round 1
// baseline (424.669 us; speedup 1.0000x reference)
//
#include <hip/hip_runtime.h>
#include <math.h>

#define TT 1024
#define BB 2048
#define FF 11
#define PP 256
#define NG 100

__device__ __forceinline__ float nz(float v) { return (v != v) ? 0.f : v; }

// ---------------- Phase 1: fully parallel per-(t,b) coefficient precompute ---
// Writes QC[t*BB+b] = (q0, q1, B0=beta*pi1n, B1=beta*pi0n)
__global__ __launch_bounds__(256) void phase1_kernel(
    const float* __restrict__ x, const float* __restrict__ beta_raw,
    const float* __restrict__ sigma_raw, float4* __restrict__ QC)
{
    int idx = blockIdx.x * 256 + threadIdx.x;      // idx = t*BB + b
    int b = idx & (BB - 1);
    const float* rec = x + (size_t)idx * FF;
    float a0  = nz(rec[0]);
    float a1  = nz(rec[1]);
    float r0  = nz(rec[2]);
    float r1  = nz(rec[3]);
    float cdc = nz(rec[4]);
    float cdn = nz(rec[5]);

    int pid = (int)nz(x[(size_t)b * FF + 10]);     // pid feature, t=0 row
    pid = pid < 0 ? 0 : (pid > PP - 1 ? PP - 1 : pid);
    float br = beta_raw[pid];
    float sr = sigma_raw[pid];
    // softplus (stable) + 1, clipped [1,25]
    float sp   = fmaxf(br, 0.f) + log1pf(expf(-fabsf(br)));
    float beta = fminf(fmaxf(sp + 1.f, 1.f), 25.f);
    float sig  = fminf(fmaxf(1.f / (1.f + expf(-sr)) * 0.09f + 0.01f, 0.01f), 0.1f);
    float inv_s = 1.f / (sig * 1.41421356237309505f);

    // state_beliefs(cd_current)
    float u = 0.5f * (1.f + erff((0.0f  - cdc) * inv_s));
    float v = 0.5f * (1.f + erff((-0.1f - cdc) * inv_s));
    float w = 0.5f * (1.f + erff((0.1f  - cdc) * inv_s));
    float inv = 1.f / fmaxf(w - v, 1e-10f);
    float pi0 = fminf(fmaxf((u - v) * inv, 0.f), 1.f);
    float pi1 = fminf(fmaxf((w - u) * inv, 0.f), 1.f);

    // state_beliefs(cd_next)
    u = 0.5f * (1.f + erff((0.0f  - cdn) * inv_s));
    v = 0.5f * (1.f + erff((-0.1f - cdn) * inv_s));
    w = 0.5f * (1.f + erff((0.1f  - cdn) * inv_s));
    inv = 1.f / fmaxf(w - v, 1e-10f);
    float pi0n = fminf(fmaxf((u - v) * inv, 0.f), 1.f);
    float pi1n = fminf(fmaxf((w - u) * inv, 0.f), 1.f);

    float rs = r0 * a0 + r1 * a1;
    float r  = (a0 >= a1) ? rs : 1.f - rs;         // argmax tie -> index 0
    float q0 = pi1 * r + pi0 * (1.f - r);
    float q1 = (2.f * r - 1.f) * (pi0 - pi1);
    if (!((a0 + a1) > 0.f)) { q0 = 1.f; q1 = 0.f; }  // no choice -> update = 1

    QC[idx] = make_float4(q0, q1, beta * pi1n, beta * pi0n);
}

// ---------------- Phase 2: sequential scan, 32 lanes per batch element -------
// Block = 256 (4 waves); wave w handles b = 2w, 2w+1 (lanes 0-31 / 32-63).
// Each lane owns grid slots {lig, lig+32, lig+64, lig+96}; slot 3 is a true
// zero (no clamp) for lig>=4 so the 128 slots reduce exactly to 100 points.
__global__ __launch_bounds__(256) void phase2_kernel(
    const float4* __restrict__ QC, float* __restrict__ out)
{
    const int lane = threadIdx.x & 63;
    const int wib  = threadIdx.x >> 6;
    const int W    = blockIdx.x * 4 + wib;
    const int lig  = lane & 31;
    const int grp  = lane >> 5;
    const int b    = 2 * W + grp;

    const float p0v = (float)lig        * (1.f / 99.f);
    const float p1v = (float)(lig + 32) * (1.f / 99.f);
    const float p2v = (float)(lig + 64) * (1.f / 99.f);
    const float p3v = (float)(lig + 96) * (1.f / 99.f);
    float be0 = 1.f, be1 = 1.f, be2 = 1.f;
    float be3 = (lig < 4) ? 1.f : 0.f;
    const float cl3 = (lig < 4) ? 1e-30f : 0.f;

    const float4* qp = QC + b;     // stride BB float4 per t
    float* lp = out + 2 * b;       // logits base, stride 2*BB floats per t

    constexpr int D = 16;          // prefetch depth: D * ~100cyc > HBM latency
    float4 pre[D];
    #pragma unroll
    for (int j = 0; j < D; ++j) pre[j] = qp[(size_t)j * BB];

    for (int t0 = 0; t0 < TT; t0 += D) {
        #pragma unroll
        for (int j = 0; j < D; ++j) {
            const int t = t0 + j;
            float4 q = pre[j];
            int tp = t + D; tp = (tp < TT) ? tp : 0;   // wrap: harmless reload
            pre[j] = qp[(size_t)tp * BB];

            float u0 = fmaf(q.y, p0v, q.x);
            float u1 = fmaf(q.y, p1v, q.x);
            float u2 = fmaf(q.y, p2v, q.x);
            float u3 = fmaf(q.y, p3v, q.x);
            be0 = fmaxf(be0 * u0, 1e-30f);
            be1 = fmaxf(be1 * u1, 1e-30f);
            be2 = fmaxf(be2 * u2, 1e-30f);
            be3 = fmaxf(be3 * u3, cl3);

            float S  = (be0 + be1) + (be2 + be3);
            float Sp = fmaf(be0, p0v, fmaf(be1, p1v, fmaf(be2, p2v, be3 * p3v)));
            #pragma unroll
            for (int k = 1; k < 32; k <<= 1) {
                S  += __shfl_xor(S,  k, 32);
                Sp += __shfl_xor(Sp, k, 32);
            }
            float E  = Sp * __builtin_amdgcn_rcpf(S);
            float A  = q.w - q.z;                     // beta*(pi0n - pi1n)
            float l0 = fmaf(A, E, q.z);
            float l1 = fmaf(-A, E, q.w);
            if (lig == 0) {                            // lanes 0 and 32
                *(float2*)(lp + (size_t)t * (2 * BB)) = make_float2(l0, l1);
            }
        }
    }

    // final belief carry: out[T*B*2 + b*100 + i]
    float* bel = out + (size_t)TT * BB * 2 + (size_t)b * NG;
    bel[lig]      = be0;
    bel[lig + 32] = be1;
    bel[lig + 64] = be2;
    if (lig < 4) bel[lig + 96] = be3;
}

extern "C" void kernel_launch(void* const* d_in, const int* in_sizes, int n_in,
                              void* d_out, int out_size, void* d_ws, size_t ws_size,
                              hipStream_t stream)
{
    const float* x         = (const float*)d_in[0];
    const float* beta_raw  = (const float*)d_in[1];
    const float* sigma_raw = (const float*)d_in[2];
    float* out = (float*)d_out;
    float4* QC = (float4*)d_ws;    // needs T*B*16 = 32 MiB of workspace

    phase1_kernel<<<(TT * BB) / 256, 256, 0, stream>>>(x, beta_raw, sigma_raw, QC);
    phase2_kernel<<<BB / 8, 256, 0, stream>>>(QC, out);
}

// Round 2
// 267.851 us; speedup vs baseline: 1.5855x; 1.5855x over previous
//
#include <hip/hip_runtime.h>
#include <math.h>

#define TT 1024
#define BB 2048
#define FF 11
#define PP 256
#define NG 100
#define J  8

__device__ __forceinline__ float nz(float v) { return (v != v) ? 0.f : v; }

// ---------------- Phase 1: fully parallel per-(t,b) coefficient precompute ---
// Writes QC[t*BB+b] = (q0, q1, B0=beta*pi1n, B1=beta*pi0n)
__global__ __launch_bounds__(256) void phase1_kernel(
    const float* __restrict__ x, const float* __restrict__ beta_raw,
    const float* __restrict__ sigma_raw, float4* __restrict__ QC)
{
    __shared__ float s[256 * FF];          // 11264 B staging
    const int tid = threadIdx.x;
    const size_t base = (size_t)blockIdx.x * (256 * FF);
    #pragma unroll
    for (int k = 0; k < FF; ++k)           // fully coalesced global loads
        s[k * 256 + tid] = x[base + k * 256 + tid];
    __syncthreads();

    const int idx = blockIdx.x * 256 + tid;   // idx = t*BB + b
    const int b   = idx & (BB - 1);
    const float* rec = s + tid * FF;          // stride 11: coprime 32 -> no conflicts
    float a0  = nz(rec[0]);
    float a1  = nz(rec[1]);
    float r0  = nz(rec[2]);
    float r1  = nz(rec[3]);
    float cdc = nz(rec[4]);
    float cdn = nz(rec[5]);

    int pid = (int)nz(x[(size_t)b * FF + 10]);   // t=0 row, 90 KB region: L2-resident
    pid = pid < 0 ? 0 : (pid > PP - 1 ? PP - 1 : pid);
    float br = beta_raw[pid];
    float sr = sigma_raw[pid];
    float sp   = fmaxf(br, 0.f) + log1pf(expf(-fabsf(br)));
    float beta = fminf(fmaxf(sp + 1.f, 1.f), 25.f);
    float sig  = fminf(fmaxf(1.f / (1.f + expf(-sr)) * 0.09f + 0.01f, 0.01f), 0.1f);
    float inv_s = 1.f / (sig * 1.41421356237309505f);

    float u = 0.5f * (1.f + erff((0.0f  - cdc) * inv_s));
    float v = 0.5f * (1.f + erff((-0.1f - cdc) * inv_s));
    float w = 0.5f * (1.f + erff((0.1f  - cdc) * inv_s));
    float inv = 1.f / fmaxf(w - v, 1e-10f);
    float pi0 = fminf(fmaxf((u - v) * inv, 0.f), 1.f);
    float pi1 = fminf(fmaxf((w - u) * inv, 0.f), 1.f);

    u = 0.5f * (1.f + erff((0.0f  - cdn) * inv_s));
    v = 0.5f * (1.f + erff((-0.1f - cdn) * inv_s));
    w = 0.5f * (1.f + erff((0.1f  - cdn) * inv_s));
    inv = 1.f / fmaxf(w - v, 1e-10f);
    float pi0n = fminf(fmaxf((u - v) * inv, 0.f), 1.f);
    float pi1n = fminf(fmaxf((w - u) * inv, 0.f), 1.f);

    float rs = r0 * a0 + r1 * a1;
    float r  = (a0 >= a1) ? rs : 1.f - rs;
    float q0 = pi1 * r + pi0 * (1.f - r);
    float q1 = (2.f * r - 1.f) * (pi0 - pi1);
    if (!((a0 + a1) > 0.f)) { q0 = 1.f; q1 = 0.f; }

    QC[idx] = make_float4(q0, q1, beta * pi1n, beta * pi0n);
}

// ---------------- DPP 32-lane-group sum: pure VALU, no LDS pipe --------------
template <int CTRL, int RMASK>
__device__ __forceinline__ float dpp_add(float v) {
    int t = __builtin_amdgcn_update_dpp(0, __float_as_int(v), CTRL, RMASK, 0xF, true);
    return v + __int_as_float(t);
}
// After this, lanes 16-31 hold the lane0-31 total; lanes 48-63 the lane32-63 total.
__device__ __forceinline__ float red32(float v) {
    v = dpp_add<0xB1,  0xF>(v);   // quad_perm [1,0,3,2]  : xor 1
    v = dpp_add<0x4E,  0xF>(v);   // quad_perm [2,3,0,1]  : xor 2
    v = dpp_add<0x141, 0xF>(v);   // row_half_mirror      : xor 4 (quads equal)
    v = dpp_add<0x140, 0xF>(v);   // row_mirror           : xor 8 (octs equal)
    v = dpp_add<0x142, 0xA>(v);   // row_bcast15, rows 1&3: cross-16 within 32
    return v;
}

// ---------------- Phase 2: sequential scan, 32 lanes per batch element -------
// Wave w handles b = 2w, 2w+1 (lanes 0-31 / 32-63). Lane owns grid slots
// {lig, lig+32, lig+64, lig+96}; slot 3 is a hard zero for lig>=4.
// Reductions are batched J steps deep (they don't feed the recursion),
// done with DPP adds so the only per-step serial chain is fma->mul->max.
__global__ __launch_bounds__(256) void phase2_kernel(
    const float4* __restrict__ QC, float* __restrict__ out)
{
    const int lane = threadIdx.x & 63;
    const int wib  = threadIdx.x >> 6;
    const int W    = blockIdx.x * 4 + wib;
    const int lig  = lane & 31;
    const int b    = 2 * W + (lane >> 5);

    const float p0v = (float)lig        * (1.f / 99.f);
    const float p1v = (float)(lig + 32) * (1.f / 99.f);
    const float p2v = (float)(lig + 64) * (1.f / 99.f);
    const float p3v = (float)(lig + 96) * (1.f / 99.f);
    float be0 = 1.f, be1 = 1.f, be2 = 1.f;
    float be3 = (lig < 4) ? 1.f : 0.f;
    const float cl3 = (lig < 4) ? 1e-30f : 0.f;

    const float4* qp = QC + b;     // stride BB float4 per t
    float* lp = out + 2 * b;       // logits base, stride 2*BB floats per t

    float4 pre[J], nxt[J];
    #pragma unroll
    for (int j = 0; j < J; ++j) pre[j] = qp[(size_t)j * BB];
    #pragma unroll
    for (int j = 0; j < J; ++j) nxt[j] = qp[(size_t)(J + j) * BB];

#define FWD(BUF, T0, TPRE)                                                    \
    {                                                                         \
        float S[J], Spp[J], Zv[J], Wv[J];                                     \
        _Pragma("unroll")                                                     \
        for (int j = 0; j < J; ++j) {                                         \
            float4 q = BUF[j];                                                \
            int tp = (TPRE) + j; if (tp >= TT) tp -= TT;                      \
            BUF[j] = qp[(size_t)tp * BB];                                     \
            float u0 = fmaf(q.y, p0v, q.x);                                   \
            float u1 = fmaf(q.y, p1v, q.x);                                   \
            float u2 = fmaf(q.y, p2v, q.x);                                   \
            float u3 = fmaf(q.y, p3v, q.x);                                   \
            be0 = fmaxf(be0 * u0, 1e-30f);                                    \
            be1 = fmaxf(be1 * u1, 1e-30f);                                    \
            be2 = fmaxf(be2 * u2, 1e-30f);                                    \
            be3 = fmaxf(be3 * u3, cl3);                                       \
            S[j]   = (be0 + be1) + (be2 + be3);                               \
            Spp[j] = fmaf(be0, p0v, fmaf(be1, p1v, fmaf(be2, p2v, be3 * p3v)));\
            Zv[j]  = q.z;                                                     \
            Wv[j]  = q.w;                                                     \
        }                                                                     \
        _Pragma("unroll")                                                     \
        for (int j = 0; j < J; ++j) {                                         \
            float st = red32(S[j]);                                           \
            float sp = red32(Spp[j]);                                         \
            float E  = sp * __builtin_amdgcn_rcpf(st);                        \
            float A  = Wv[j] - Zv[j];                                         \
            float l0 = fmaf(A, E, Zv[j]);                                     \
            float l1 = fmaf(-A, E, Wv[j]);                                    \
            if (lig == 16)                                                    \
                *(float2*)(lp + (size_t)((T0) + j) * (2 * BB)) =              \
                    make_float2(l0, l1);                                      \
        }                                                                     \
    }

    for (int t0 = 0; t0 < TT; t0 += 2 * J) {
        FWD(pre, t0,     t0 + 2 * J)      // consume t0..t0+7,  prefetch +16
        FWD(nxt, t0 + J, t0 + 3 * J)      // consume +8..+15,   prefetch +24
    }
#undef FWD

    // final belief carry: out[T*B*2 + b*100 + i]
    float* bel = out + (size_t)TT * BB * 2 + (size_t)b * NG;
    bel[lig]      = be0;
    bel[lig + 32] = be1;
    bel[lig + 64] = be2;
    if (lig < 4) bel[lig + 96] = be3;
}

extern "C" void kernel_launch(void* const* d_in, const int* in_sizes, int n_in,
                              void* d_out, int out_size, void* d_ws, size_t ws_size,
                              hipStream_t stream)
{
    const float* x         = (const float*)d_in[0];
    const float* beta_raw  = (const float*)d_in[1];
    const float* sigma_raw = (const float*)d_in[2];
    float* out = (float*)d_out;
    float4* QC = (float4*)d_ws;    // T*B*16 = 32 MiB of workspace

    phase1_kernel<<<(TT * BB) / 256, 256, 0, stream>>>(x, beta_raw, sigma_raw, QC);
    phase2_kernel<<<BB / 8, 256, 0, stream>>>(QC, out);
}

// Round 3
// 255.604 us; speedup vs baseline: 1.6614x; 1.0479x over previous
//
#include <hip/hip_runtime.h>
#include <math.h>

#define TT  1024
#define BB  2048
#define FF  11
#define PP  256
#define NG  100
#define NCH 8            // chunks over T
#define LCH (TT / NCH)   // 128 steps per chunk
#define JJ  4            // reduction batch / prefetch depth

__device__ __forceinline__ float nz(float v) { return (v != v) ? 0.f : v; }

// Branch-free erf, Abramowitz-Stegun 7.1.26, |err| <= 1.5e-7 (abs).
__device__ __forceinline__ float erf_fast(float x) {
    float ax = fabsf(x);
    float t  = __builtin_amdgcn_rcpf(fmaf(0.3275911f, ax, 1.f));
    float y  = fmaf(fmaf(fmaf(fmaf(1.061405429f, t, -1.453152027f), t,
                              1.421413741f), t, -0.284496736f), t, 0.254829592f);
    y *= t;
    float r = fmaf(-y, __expf(-ax * ax), 1.f);
    return copysignf(r, x);
}

// ---------------- Phase 1: per-(t,b) coefficient precompute ------------------
// QC[t*BB+b] = (q0, q1, B0=beta*pi1n, B1=beta*pi0n)
__global__ __launch_bounds__(256) void phase1_kernel(
    const float* __restrict__ x, const float* __restrict__ beta_raw,
    const float* __restrict__ sigma_raw, float4* __restrict__ QC)
{
    __shared__ float s[256 * FF];
    const int tid = threadIdx.x;
    const size_t base = (size_t)blockIdx.x * (256 * FF);
    #pragma unroll
    for (int k = 0; k < FF; ++k)
        s[k * 256 + tid] = x[base + k * 256 + tid];
    __syncthreads();

    const int idx = blockIdx.x * 256 + tid;   // idx = t*BB + b
    const int b   = idx & (BB - 1);
    const float* rec = s + tid * FF;          // stride 11, coprime 32
    float a0  = nz(rec[0]);
    float a1  = nz(rec[1]);
    float r0  = nz(rec[2]);
    float r1  = nz(rec[3]);
    float cdc = nz(rec[4]);
    float cdn = nz(rec[5]);

    int pid = (int)nz(x[(size_t)b * FF + 10]);
    pid = pid < 0 ? 0 : (pid > PP - 1 ? PP - 1 : pid);
    float br = beta_raw[pid];
    float sr = sigma_raw[pid];
    float sp   = fmaxf(br, 0.f) + log1pf(__expf(-fabsf(br)));
    float beta = fminf(fmaxf(sp + 1.f, 1.f), 25.f);
    float sig  = fminf(fmaxf(__builtin_amdgcn_rcpf(1.f + __expf(-sr)) * 0.09f + 0.01f,
                             0.01f), 0.1f);
    float inv_s = 1.f / (sig * 1.41421356237309505f);

    float u = 0.5f * (1.f + erf_fast((0.0f  - cdc) * inv_s));
    float v = 0.5f * (1.f + erf_fast((-0.1f - cdc) * inv_s));
    float w = 0.5f * (1.f + erf_fast((0.1f  - cdc) * inv_s));
    float inv = 1.f / fmaxf(w - v, 1e-10f);
    float pi0 = fminf(fmaxf((u - v) * inv, 0.f), 1.f);
    float pi1 = fminf(fmaxf((w - u) * inv, 0.f), 1.f);

    u = 0.5f * (1.f + erf_fast((0.0f  - cdn) * inv_s));
    v = 0.5f * (1.f + erf_fast((-0.1f - cdn) * inv_s));
    w = 0.5f * (1.f + erf_fast((0.1f  - cdn) * inv_s));
    inv = 1.f / fmaxf(w - v, 1e-10f);
    float pi0n = fminf(fmaxf((u - v) * inv, 0.f), 1.f);
    float pi1n = fminf(fmaxf((w - u) * inv, 0.f), 1.f);

    float rs = r0 * a0 + r1 * a1;
    float r  = (a0 >= a1) ? rs : 1.f - rs;
    float q0 = pi1 * r + pi0 * (1.f - r);
    float q1 = (2.f * r - 1.f) * (pi0 - pi1);
    if (!((a0 + a1) > 0.f)) { q0 = 1.f; q1 = 0.f; }

    QC[idx] = make_float4(q0, q1, beta * pi1n, beta * pi0n);
}

// ---------------- DPP 32-lane-group sum (pure VALU) --------------------------
template <int CTRL, int RMASK>
__device__ __forceinline__ float dpp_add(float v) {
    int t = __builtin_amdgcn_update_dpp(0, __float_as_int(v), CTRL, RMASK, 0xF, true);
    return v + __int_as_float(t);
}
// lanes 16-31 hold lane0-31 total; lanes 48-63 hold lane32-63 total
__device__ __forceinline__ float red32(float v) {
    v = dpp_add<0xB1,  0xF>(v);
    v = dpp_add<0x4E,  0xF>(v);
    v = dpp_add<0x141, 0xF>(v);
    v = dpp_add<0x140, 0xF>(v);
    v = dpp_add<0x142, 0xA>(v);
    return v;
}

// The clamped recursion be' = max(be*u, 1e-30) composes: over a chunk,
// be_out = max(be_in * U, C) with U = prod(u), C = max-scan of the floor.
// u in [0,1] => U non-increasing; if the max picks be_in*U then U >= 1e-30,
// so U is never denormal when it matters. Exact semantics, scan-able over T.

// ---------------- Phase A: per-chunk (U,C) composition, 8 waves/SIMD ---------
// Wave W: pair = W & 1023 (b = 2*pair + lane/32), chunk c = W >> 10.
__global__ __launch_bounds__(256, 6) void phaseA_kernel(
    const float4* __restrict__ QC, float2* __restrict__ UC)
{
    const int lane = threadIdx.x & 63;
    const int wib  = threadIdx.x >> 6;
    const int W    = blockIdx.x * 4 + wib;
    const int pair = W & 1023;
    const int c    = W >> 10;
    const int lig  = lane & 31;
    const int b    = 2 * pair + (lane >> 5);
    const int t0   = c * LCH;

    const float p0v = (float)lig        * (1.f / 99.f);
    const float p1v = (float)(lig + 32) * (1.f / 99.f);
    const float p2v = (float)(lig + 64) * (1.f / 99.f);
    const float p3v = (float)(lig + 96) * (1.f / 99.f);

    float U0 = 1.f, U1 = 1.f, U2 = 1.f, U3 = 1.f;
    float C0 = 0.f, C1 = 0.f, C2 = 0.f, C3 = 0.f;

    const float4* qp = QC + b;
    float4 pre[JJ];
    #pragma unroll
    for (int j = 0; j < JJ; ++j) pre[j] = qp[(size_t)(t0 + j) * BB];

    for (int tt = 0; tt < LCH; tt += JJ) {
        #pragma unroll
        for (int j = 0; j < JJ; ++j) {
            float4 q = pre[j];
            int tg = (t0 + tt + j + JJ) & (TT - 1);     // wrap: harmless reload
            pre[j] = qp[(size_t)tg * BB];
            float u0 = fmaf(q.y, p0v, q.x);
            float u1 = fmaf(q.y, p1v, q.x);
            float u2 = fmaf(q.y, p2v, q.x);
            float u3 = fmaf(q.y, p3v, q.x);
            U0 *= u0; C0 = fmaxf(C0 * u0, 1e-30f);
            U1 *= u1; C1 = fmaxf(C1 * u1, 1e-30f);
            U2 *= u2; C2 = fmaxf(C2 * u2, 1e-30f);
            U3 *= u3; C3 = fmaxf(C3 * u3, 1e-30f);
        }
    }

    // UC[(c*BB + b)*100 + i], i = lig + 32*s (only real slots i<100 stored)
    float2* dst = UC + ((size_t)c * BB + b) * NG;
    dst[lig]      = make_float2(U0, C0);
    dst[lig + 32] = make_float2(U1, C1);
    dst[lig + 64] = make_float2(U2, C2);
    if (lig < 4) dst[lig + 96] = make_float2(U3, C3);
}

// ---------------- Phase B: 8-step scan over chunks per (b,i) -----------------
__global__ __launch_bounds__(256) void phaseB_kernel(
    const float2* __restrict__ UC, float* __restrict__ BE)
{
    const int flat = blockIdx.x * 256 + threadIdx.x;   // flat = b*100 + i
    float be = 1.f;
    #pragma unroll
    for (int c = 0; c < NCH; ++c) {
        BE[(size_t)c * (BB * NG) + flat] = be;
        float2 uc = UC[(size_t)c * (BB * NG) + flat];
        be = fmaxf(be * uc.x, uc.y);
    }
}

// ---------------- Phase C: parallel chunk re-walk, logits + carry ------------
__global__ __launch_bounds__(256, 6) void phaseC_kernel(
    const float4* __restrict__ QC, const float* __restrict__ BE,
    float* __restrict__ out)
{
    const int lane = threadIdx.x & 63;
    const int wib  = threadIdx.x >> 6;
    const int W    = blockIdx.x * 4 + wib;
    const int pair = W & 1023;
    const int c    = W >> 10;
    const int lig  = lane & 31;
    const int b    = 2 * pair + (lane >> 5);
    const int t0   = c * LCH;

    const float p0v = (float)lig        * (1.f / 99.f);
    const float p1v = (float)(lig + 32) * (1.f / 99.f);
    const float p2v = (float)(lig + 64) * (1.f / 99.f);
    const float p3v = (float)(lig + 96) * (1.f / 99.f);

    const float* ebase = BE + ((size_t)c * BB + b) * NG;
    float be0 = ebase[lig];
    float be1 = ebase[lig + 32];
    float be2 = ebase[lig + 64];
    float be3 = (lig < 4) ? ebase[lig + 96] : 0.f;
    const float cl3 = (lig < 4) ? 1e-30f : 0.f;

    const float4* qp = QC + b;
    float* lp = out + 2 * b;

    float4 pre[JJ];
    #pragma unroll
    for (int j = 0; j < JJ; ++j) pre[j] = qp[(size_t)(t0 + j) * BB];

    for (int tt = 0; tt < LCH; tt += JJ) {
        float S[JJ], Sp[JJ], Zv[JJ], Wv[JJ];
        #pragma unroll
        for (int j = 0; j < JJ; ++j) {
            float4 q = pre[j];
            int tg = (t0 + tt + j + JJ) & (TT - 1);
            pre[j] = qp[(size_t)tg * BB];
            float u0 = fmaf(q.y, p0v, q.x);
            float u1 = fmaf(q.y, p1v, q.x);
            float u2 = fmaf(q.y, p2v, q.x);
            float u3 = fmaf(q.y, p3v, q.x);
            be0 = fmaxf(be0 * u0, 1e-30f);
            be1 = fmaxf(be1 * u1, 1e-30f);
            be2 = fmaxf(be2 * u2, 1e-30f);
            be3 = fmaxf(be3 * u3, cl3);
            S[j]  = (be0 + be1) + (be2 + be3);
            Sp[j] = fmaf(be0, p0v, fmaf(be1, p1v, fmaf(be2, p2v, be3 * p3v)));
            Zv[j] = q.z;
            Wv[j] = q.w;
        }
        #pragma unroll
        for (int j = 0; j < JJ; ++j) {
            float st = red32(S[j]);
            float sr = red32(Sp[j]);
            float E  = sr * __builtin_amdgcn_rcpf(st);
            float A  = Wv[j] - Zv[j];
            float l0 = fmaf(A, E, Zv[j]);
            float l1 = fmaf(-A, E, Wv[j]);
            if (lig == 16)
                *(float2*)(lp + (size_t)(t0 + tt + j) * (2 * BB)) =
                    make_float2(l0, l1);
        }
    }

    if (c == NCH - 1) {   // final belief carry: out[T*B*2 + b*100 + i]
        float* bel = out + (size_t)TT * BB * 2 + (size_t)b * NG;
        bel[lig]      = be0;
        bel[lig + 32] = be1;
        bel[lig + 64] = be2;
        if (lig < 4) bel[lig + 96] = be3;
    }
}

extern "C" void kernel_launch(void* const* d_in, const int* in_sizes, int n_in,
                              void* d_out, int out_size, void* d_ws, size_t ws_size,
                              hipStream_t stream)
{
    const float* x         = (const float*)d_in[0];
    const float* beta_raw  = (const float*)d_in[1];
    const float* sigma_raw = (const float*)d_in[2];
    float* out = (float*)d_out;

    // workspace layout: QC (32 MiB) | UC (13.1 MB) | BE (6.6 MB)  ~= 53 MB
    char* ws = (char*)d_ws;
    float4* QC = (float4*)ws;
    float2* UC = (float2*)(ws + (size_t)TT * BB * 16);
    float*  BE = (float*) (ws + (size_t)TT * BB * 16 + (size_t)NCH * BB * NG * 8);

    phase1_kernel<<<(TT * BB) / 256, 256, 0, stream>>>(x, beta_raw, sigma_raw, QC);
    phaseA_kernel<<<(BB / 2) * NCH / 4, 256, 0, stream>>>(QC, UC);
    phaseB_kernel<<<(BB * NG) / 256, 256, 0, stream>>>(UC, BE);
    phaseC_kernel<<<(BB / 2) * NCH / 4, 256, 0, stream>>>(QC, BE, out);
}

// Round 5
// 247.375 us; speedup vs baseline: 1.7167x; 1.0333x over previous
//
#include <hip/hip_runtime.h>
#include <math.h>

#define TT  1024
#define BB  2048
#define FF  11
#define PP  256
#define NG  100
#define NCH 8            // chunks over T
#define LCH (TT / NCH)   // 128 steps per chunk
#define JJ  4            // unroll / prefetch depth

typedef float f32x2 __attribute__((ext_vector_type(2)));

__device__ __forceinline__ float nz(float v) { return (v != v) ? 0.f : v; }

// Branch-free erf, Abramowitz-Stegun 7.1.26, |err| <= 1.5e-7 (abs).
__device__ __forceinline__ float erf_fast(float x) {
    float ax = fabsf(x);
    float t  = __builtin_amdgcn_rcpf(fmaf(0.3275911f, ax, 1.f));
    float y  = fmaf(fmaf(fmaf(fmaf(1.061405429f, t, -1.453152027f), t,
                              1.421413741f), t, -0.284496736f), t, 0.254829592f);
    y *= t;
    float r = fmaf(-y, __expf(-ax * ax), 1.f);
    return copysignf(r, x);
}

// ---------------- Phase 1: per-(t,b) coefficient precompute ------------------
// QC[t*BB+b] = (q0, q1, B0=beta*pi1n, B1=beta*pi0n)
__global__ __launch_bounds__(256) void phase1_kernel(
    const float* __restrict__ x, const float* __restrict__ beta_raw,
    const float* __restrict__ sigma_raw, float4* __restrict__ QC)
{
    __shared__ float s[256 * FF];
    const int tid = threadIdx.x;
    const size_t base = (size_t)blockIdx.x * (256 * FF);
    #pragma unroll
    for (int k = 0; k < FF; ++k)
        s[k * 256 + tid] = x[base + k * 256 + tid];
    __syncthreads();

    const int idx = blockIdx.x * 256 + tid;   // idx = t*BB + b
    const int b   = idx & (BB - 1);
    const float* rec = s + tid * FF;          // stride 11, coprime 32
    float a0  = nz(rec[0]);
    float a1  = nz(rec[1]);
    float r0  = nz(rec[2]);
    float r1  = nz(rec[3]);
    float cdc = nz(rec[4]);
    float cdn = nz(rec[5]);

    int pid = (int)nz(x[(size_t)b * FF + 10]);
    pid = pid < 0 ? 0 : (pid > PP - 1 ? PP - 1 : pid);
    float br = beta_raw[pid];
    float sr = sigma_raw[pid];
    float sp   = fmaxf(br, 0.f) + log1pf(__expf(-fabsf(br)));
    float beta = fminf(fmaxf(sp + 1.f, 1.f), 25.f);
    float sig  = fminf(fmaxf(__builtin_amdgcn_rcpf(1.f + __expf(-sr)) * 0.09f + 0.01f,
                             0.01f), 0.1f);
    float inv_s = 1.f / (sig * 1.41421356237309505f);

    float u = 0.5f * (1.f + erf_fast((0.0f  - cdc) * inv_s));
    float v = 0.5f * (1.f + erf_fast((-0.1f - cdc) * inv_s));
    float w = 0.5f * (1.f + erf_fast((0.1f  - cdc) * inv_s));
    float inv = 1.f / fmaxf(w - v, 1e-10f);
    float pi0 = fminf(fmaxf((u - v) * inv, 0.f), 1.f);
    float pi1 = fminf(fmaxf((w - u) * inv, 0.f), 1.f);

    u = 0.5f * (1.f + erf_fast((0.0f  - cdn) * inv_s));
    v = 0.5f * (1.f + erf_fast((-0.1f - cdn) * inv_s));
    w = 0.5f * (1.f + erf_fast((0.1f  - cdn) * inv_s));
    inv = 1.f / fmaxf(w - v, 1e-10f);
    float pi0n = fminf(fmaxf((u - v) * inv, 0.f), 1.f);
    float pi1n = fminf(fmaxf((w - u) * inv, 0.f), 1.f);

    float rs = r0 * a0 + r1 * a1;
    float r  = (a0 >= a1) ? rs : 1.f - rs;
    float q0 = pi1 * r + pi0 * (1.f - r);
    float q1 = (2.f * r - 1.f) * (pi0 - pi1);
    if (!((a0 + a1) > 0.f)) { q0 = 1.f; q1 = 0.f; }

    QC[idx] = make_float4(q0, q1, beta * pi1n, beta * pi0n);
}

// ---------------- DPP 32-lane-group sum (pure VALU) --------------------------
template <int CTRL, int RMASK>
__device__ __forceinline__ float dpp_add(float v) {
    int t = __builtin_amdgcn_update_dpp(0, __float_as_int(v), CTRL, RMASK, 0xF, true);
    return v + __int_as_float(t);
}
// lanes 16-31 hold lane0-31 total; lanes 48-63 hold lane32-63 total
__device__ __forceinline__ float red32(float v) {
    v = dpp_add<0xB1,  0xF>(v);
    v = dpp_add<0x4E,  0xF>(v);
    v = dpp_add<0x141, 0xF>(v);
    v = dpp_add<0x140, 0xF>(v);
    v = dpp_add<0x142, 0xA>(v);
    return v;
}

// be' = max(be*u, 1e-30) composes over a chunk as be_out = max(be_in*U, C):
// U = prod(u), C = max-scan of floor. Exact semantics, scan-able over T.

// ---------------- Phase A: per-chunk (U,C) composition -----------------------
// Wave W: pair = W & 1023 (b = 2*pair + lane/32), chunk c = W >> 10.
__global__ __launch_bounds__(256) void phaseA_kernel(
    const float4* __restrict__ QC, float2* __restrict__ UC)
{
    const int lane = threadIdx.x & 63;
    const int wib  = threadIdx.x >> 6;
    const int W    = blockIdx.x * 4 + wib;
    const int pair = W & 1023;
    const int c    = W >> 10;
    const int lig  = lane & 31;
    const int b    = 2 * pair + (lane >> 5);
    const int t0   = c * LCH;

    const f32x2 p01 = { (float)lig        * (1.f / 99.f),
                        (float)(lig + 32) * (1.f / 99.f) };
    const f32x2 p23 = { (float)(lig + 64) * (1.f / 99.f),
                        (float)(lig + 96) * (1.f / 99.f) };
    const f32x2 cl01 = { 1e-30f, 1e-30f };
    const f32x2 cl23 = { 1e-30f, (lig < 4) ? 1e-30f : 0.f };

    f32x2 U01 = { 1.f, 1.f }, U23 = { 1.f, 1.f };
    f32x2 C01 = { 0.f, 0.f }, C23 = { 0.f, 0.f };

    const char* QCb = (const char*)QC;
    unsigned off = ((unsigned)t0 * BB + (unsigned)b) * 16u;   // byte offset, <32MB

    float4 pre[JJ];
    #pragma unroll
    for (int j = 0; j < JJ; ++j)
        pre[j] = *(const float4*)(QCb + (off + (unsigned)j * (BB * 16u)));
    off += JJ * (BB * 16u);

    for (int tt = 0; tt < LCH; tt += JJ) {
        #pragma unroll
        for (int j = 0; j < JJ; ++j) {
            float4 q = pre[j];
            // overrun prefetch (last outer iter) lands in UC region: never used
            pre[j] = *(const float4*)(QCb + (off + (unsigned)j * (BB * 16u)));
            f32x2 qx = { q.x, q.x }, qy = { q.y, q.y };
            f32x2 u01 = qy * p01 + qx;               // v_pk_fma_f32
            f32x2 u23 = qy * p23 + qx;
            U01 *= u01;
            U23 *= u23;
            C01 = __builtin_elementwise_max(C01 * u01, cl01);
            C23 = __builtin_elementwise_max(C23 * u23, cl23);
        }
        off += JJ * (BB * 16u);
    }

    float2* dst = UC + ((size_t)c * BB + b) * NG;
    dst[lig]      = make_float2(U01.x, C01.x);
    dst[lig + 32] = make_float2(U01.y, C01.y);
    dst[lig + 64] = make_float2(U23.x, C23.x);
    if (lig < 4) dst[lig + 96] = make_float2(U23.y, C23.y);
}

// ---------------- Phase B: 8-step scan over chunks per (b,i) -----------------
__global__ __launch_bounds__(256) void phaseB_kernel(
    const float2* __restrict__ UC, float* __restrict__ BE)
{
    const int flat = blockIdx.x * 256 + threadIdx.x;   // flat = b*100 + i
    float be = 1.f;
    #pragma unroll
    for (int c = 0; c < NCH; ++c) {
        BE[(size_t)c * (BB * NG) + flat] = be;
        float2 uc = UC[(size_t)c * (BB * NG) + flat];
        be = fmaxf(be * uc.x, uc.y);
    }
}

// ---------------- Phase C: parallel chunk re-walk, logits + carry ------------
__global__ __launch_bounds__(256) void phaseC_kernel(
    const float4* __restrict__ QC, const float* __restrict__ BE,
    float* __restrict__ out)
{
    const int lane = threadIdx.x & 63;
    const int wib  = threadIdx.x >> 6;
    const int W    = blockIdx.x * 4 + wib;
    const int pair = W & 1023;
    const int c    = W >> 10;
    const int lig  = lane & 31;
    const int b    = 2 * pair + (lane >> 5);
    const int t0   = c * LCH;

    const f32x2 p01 = { (float)lig        * (1.f / 99.f),
                        (float)(lig + 32) * (1.f / 99.f) };
    const f32x2 p23 = { (float)(lig + 64) * (1.f / 99.f),
                        (float)(lig + 96) * (1.f / 99.f) };
    const f32x2 cl01 = { 1e-30f, 1e-30f };
    const f32x2 cl23 = { 1e-30f, (lig < 4) ? 1e-30f : 0.f };

    const float* ebase = BE + ((size_t)c * BB + b) * NG;
    f32x2 be01 = { ebase[lig], ebase[lig + 32] };
    f32x2 be23 = { ebase[lig + 64], (lig < 4) ? ebase[lig + 96] : 0.f };

    const char* QCb = (const char*)QC;
    char* outb = (char*)out;
    unsigned off  = ((unsigned)t0 * BB + (unsigned)b) * 16u;       // QC bytes
    unsigned soff = ((unsigned)t0 * (2 * BB) + 2 * (unsigned)b) * 4u; // out bytes

    float4 pre[JJ];
    #pragma unroll
    for (int j = 0; j < JJ; ++j)
        pre[j] = *(const float4*)(QCb + (off + (unsigned)j * (BB * 16u)));
    off += JJ * (BB * 16u);

    for (int tt = 0; tt < LCH; tt += JJ) {
        float S[JJ], Sp[JJ], Zv[JJ], Wv[JJ];
        #pragma unroll
        for (int j = 0; j < JJ; ++j) {
            float4 q = pre[j];
            pre[j] = *(const float4*)(QCb + (off + (unsigned)j * (BB * 16u)));
            f32x2 qx = { q.x, q.x }, qy = { q.y, q.y };
            f32x2 u01 = qy * p01 + qx;               // v_pk_fma_f32
            f32x2 u23 = qy * p23 + qx;
            be01 = __builtin_elementwise_max(be01 * u01, cl01);
            be23 = __builtin_elementwise_max(be23 * u23, cl23);
            f32x2 s2  = be01 + be23;                 // v_pk_add_f32
            f32x2 sp2 = be23 * p23 + be01 * p01;     // pk_mul + pk_fma
            S[j]  = s2.x + s2.y;
            Sp[j] = sp2.x + sp2.y;
            Zv[j] = q.z;
            Wv[j] = q.w;
        }
        off += JJ * (BB * 16u);
        #pragma unroll
        for (int j = 0; j < JJ; ++j) {
            float st = red32(S[j]);
            float sr = red32(Sp[j]);
            float E  = sr * __builtin_amdgcn_rcpf(st);
            float A  = Wv[j] - Zv[j];
            float l0 = fmaf(A, E, Zv[j]);
            float l1 = fmaf(-A, E, Wv[j]);
            if (lig == 16)
                *(float2*)(outb + (soff + (unsigned)j * (2 * BB * 4u))) =
                    make_float2(l0, l1);
        }
        soff += JJ * (2 * BB * 4u);
    }

    if (c == NCH - 1) {   // final belief carry: out[T*B*2 + b*100 + i]
        float* bel = out + (size_t)TT * BB * 2 + (size_t)b * NG;
        bel[lig]      = be01.x;
        bel[lig + 32] = be01.y;
        bel[lig + 64] = be23.x;
        if (lig < 4) bel[lig + 96] = be23.y;
    }
}

extern "C" void kernel_launch(void* const* d_in, const int* in_sizes, int n_in,
                              void* d_out, int out_size, void* d_ws, size_t ws_size,
                              hipStream_t stream)
{
    const float* x         = (const float*)d_in[0];
    const float* beta_raw  = (const float*)d_in[1];
    const float* sigma_raw = (const float*)d_in[2];
    float* out = (float*)d_out;

    // workspace: QC (32 MiB) | UC (13.1 MB) | BE (6.6 MB)  ~= 53 MB
    char* ws = (char*)d_ws;
    float4* QC = (float4*)ws;
    float2* UC = (float2*)(ws + (size_t)TT * BB * 16);
    float*  BE = (float*) (ws + (size_t)TT * BB * 16 + (size_t)NCH * BB * NG * 8);

    phase1_kernel<<<(TT * BB) / 256, 256, 0, stream>>>(x, beta_raw, sigma_raw, QC);
    phaseA_kernel<<<(BB / 2) * NCH / 4, 256, 0, stream>>>(QC, UC);
    phaseB_kernel<<<(BB * NG) / 256, 256, 0, stream>>>(UC, BE);
    phaseC_kernel<<<(BB / 2) * NCH / 4, 256, 0, stream>>>(QC, BE, out);
}

// Round 6
// 217.943 us; speedup vs baseline: 1.9485x; 1.1350x over previous
//
#include <hip/hip_runtime.h>
#include <math.h>

#define TT  1024
#define BB  2048
#define FF  11
#define PP  256
#define NG  100
#define NCH 16           // chunks over T
#define LCH (TT / NCH)   // 64 steps per chunk
#define JJ  4            // unroll / prefetch depth

typedef float f32x2 __attribute__((ext_vector_type(2)));

__device__ __forceinline__ float nz(float v) { return (v != v) ? 0.f : v; }

// Branch-free erf, Abramowitz-Stegun 7.1.26, |err| <= 1.5e-7 (abs).
__device__ __forceinline__ float erf_fast(float x) {
    float ax = fabsf(x);
    float t  = __builtin_amdgcn_rcpf(fmaf(0.3275911f, ax, 1.f));
    float y  = fmaf(fmaf(fmaf(fmaf(1.061405429f, t, -1.453152027f), t,
                              1.421413741f), t, -0.284496736f), t, 0.254829592f);
    y *= t;
    float r = fmaf(-y, __expf(-ax * ax), 1.f);
    return copysignf(r, x);
}

// ---------------- Phase 1: per-(t,b) coefficient precompute ------------------
// QC[t*BB+b] = (q0, q1, B0=beta*pi1n, B1=beta*pi0n)
__global__ __launch_bounds__(256) void phase1_kernel(
    const float* __restrict__ x, const float* __restrict__ beta_raw,
    const float* __restrict__ sigma_raw, float4* __restrict__ QC)
{
    __shared__ float s[256 * FF];
    const int tid = threadIdx.x;
    const size_t base = (size_t)blockIdx.x * (256 * FF);
    {   // 256*11 floats = 704 float4, 16B-aligned (11264 B per block)
        const float4* x4 = (const float4*)(x + base);
        float4* s4 = (float4*)s;
        #pragma unroll
        for (int k = tid; k < 704; k += 256) s4[k] = x4[k];
    }
    __syncthreads();

    const int idx = blockIdx.x * 256 + tid;   // idx = t*BB + b
    const int b   = idx & (BB - 1);
    const float* rec = s + tid * FF;          // stride 11, coprime 32
    float a0  = nz(rec[0]);
    float a1  = nz(rec[1]);
    float r0  = nz(rec[2]);
    float r1  = nz(rec[3]);
    float cdc = nz(rec[4]);
    float cdn = nz(rec[5]);

    int pid = (int)nz(x[(size_t)b * FF + 10]);
    pid = pid < 0 ? 0 : (pid > PP - 1 ? PP - 1 : pid);
    float br = beta_raw[pid];
    float sr = sigma_raw[pid];
    float sp   = fmaxf(br, 0.f) + log1pf(__expf(-fabsf(br)));
    float beta = fminf(fmaxf(sp + 1.f, 1.f), 25.f);
    float sig  = fminf(fmaxf(__builtin_amdgcn_rcpf(1.f + __expf(-sr)) * 0.09f + 0.01f,
                             0.01f), 0.1f);
    float inv_s = 1.f / (sig * 1.41421356237309505f);

    float u = 0.5f * (1.f + erf_fast((0.0f  - cdc) * inv_s));
    float v = 0.5f * (1.f + erf_fast((-0.1f - cdc) * inv_s));
    float w = 0.5f * (1.f + erf_fast((0.1f  - cdc) * inv_s));
    float inv = 1.f / fmaxf(w - v, 1e-10f);
    float pi0 = fminf(fmaxf((u - v) * inv, 0.f), 1.f);
    float pi1 = fminf(fmaxf((w - u) * inv, 0.f), 1.f);

    u = 0.5f * (1.f + erf_fast((0.0f  - cdn) * inv_s));
    v = 0.5f * (1.f + erf_fast((-0.1f - cdn) * inv_s));
    w = 0.5f * (1.f + erf_fast((0.1f  - cdn) * inv_s));
    inv = 1.f / fmaxf(w - v, 1e-10f);
    float pi0n = fminf(fmaxf((u - v) * inv, 0.f), 1.f);
    float pi1n = fminf(fmaxf((w - u) * inv, 0.f), 1.f);

    float rs = r0 * a0 + r1 * a1;
    float r  = (a0 >= a1) ? rs : 1.f - rs;
    float q0 = pi1 * r + pi0 * (1.f - r);
    float q1 = (2.f * r - 1.f) * (pi0 - pi1);
    if (!((a0 + a1) > 0.f)) { q0 = 1.f; q1 = 0.f; }

    QC[idx] = make_float4(q0, q1, beta * pi1n, beta * pi0n);
}

// ---------------- DPP cross-lane adds (pure VALU) ----------------------------
template <int CTRL, int RMASK>
__device__ __forceinline__ float dpp_add(float v) {
    int t = __builtin_amdgcn_update_dpp(0, __float_as_int(v), CTRL, RMASK, 0xF, true);
    return v + __int_as_float(t);
}
// butterfly sum over aligned groups of 8 lanes; every lane gets the total
__device__ __forceinline__ float red8(float v) {
    v = dpp_add<0xB1,  0xF>(v);   // quad_perm [1,0,3,2] : xor 1
    v = dpp_add<0x4E,  0xF>(v);   // quad_perm [2,3,0,1] : xor 2
    v = dpp_add<0x141, 0xF>(v);   // row_half_mirror    : xor 4 (quads equal)
    return v;
}

// be' = max(be*u, 1e-30) composes over a chunk as be_out = max(be_in*U, C):
// U = prod(u), C = max-scan of floor. Exact semantics, scan-able over T.

// ---------------- Phase A: per-chunk (U,C) composition -----------------------
// 32 lanes per b (2 b per wave): pair = W & 1023, chunk c = W >> 10.
__global__ __launch_bounds__(256) void phaseA_kernel(
    const float4* __restrict__ QC, float2* __restrict__ UC)
{
    const int lane = threadIdx.x & 63;
    const int wib  = threadIdx.x >> 6;
    const int W    = blockIdx.x * 4 + wib;
    const int pair = W & 1023;
    const int c    = W >> 10;
    const int lig  = lane & 31;
    const int b    = 2 * pair + (lane >> 5);
    const int t0   = c * LCH;

    const f32x2 p01 = { (float)lig        * (1.f / 99.f),
                        (float)(lig + 32) * (1.f / 99.f) };
    const f32x2 p23 = { (float)(lig + 64) * (1.f / 99.f),
                        (float)(lig + 96) * (1.f / 99.f) };
    const f32x2 cl01 = { 1e-30f, 1e-30f };
    const f32x2 cl23 = { 1e-30f, (lig < 4) ? 1e-30f : 0.f };

    f32x2 U01 = { 1.f, 1.f }, U23 = { 1.f, 1.f };
    f32x2 C01 = { 0.f, 0.f }, C23 = { 0.f, 0.f };

    const char* QCb = (const char*)QC;
    unsigned off = ((unsigned)t0 * BB + (unsigned)b) * 16u;

    float4 pre[JJ];
    #pragma unroll
    for (int j = 0; j < JJ; ++j)
        pre[j] = *(const float4*)(QCb + (off + (unsigned)j * (BB * 16u)));
    off += JJ * (BB * 16u);

    for (int tt = 0; tt < LCH; tt += JJ) {
        #pragma unroll
        for (int j = 0; j < JJ; ++j) {
            float4 q = pre[j];
            // overrun prefetch (last iter) lands in UC region: never consumed
            pre[j] = *(const float4*)(QCb + (off + (unsigned)j * (BB * 16u)));
            f32x2 qx = { q.x, q.x }, qy = { q.y, q.y };
            f32x2 u01 = qy * p01 + qx;
            f32x2 u23 = qy * p23 + qx;
            U01 *= u01;
            U23 *= u23;
            C01 = __builtin_elementwise_max(C01 * u01, cl01);
            C23 = __builtin_elementwise_max(C23 * u23, cl23);
        }
        off += JJ * (BB * 16u);
    }

    float2* dst = UC + ((size_t)c * BB + b) * NG;
    dst[lig]      = make_float2(U01.x, C01.x);
    dst[lig + 32] = make_float2(U01.y, C01.y);
    dst[lig + 64] = make_float2(U23.x, C23.x);
    if (lig < 4) dst[lig + 96] = make_float2(U23.y, C23.y);
}

// ---------------- Phase B: 16-step scan over chunks per (b,i) ----------------
__global__ __launch_bounds__(256) void phaseB_kernel(
    const float2* __restrict__ UC, float* __restrict__ BE)
{
    const int flat = blockIdx.x * 256 + threadIdx.x;   // flat = b*100 + i
    float be = 1.f;
    #pragma unroll
    for (int c = 0; c < NCH; ++c) {
        BE[(size_t)c * (BB * NG) + flat] = be;
        float2 uc = UC[(size_t)c * (BB * NG) + flat];
        be = fmaxf(be * uc.x, uc.y);
    }
}

// ---------------- Phase C: parallel chunk re-walk, logits + carry ------------
// 8 lanes per b, 8 b per wave. Lane (g=lane>>3, sl=lane&7) owns 7 slot-pairs:
// pair k = grid points {sl+16k, sl+16k+8}; points >=100 are hard zeros.
__global__ __launch_bounds__(256) void phaseC_kernel(
    const float4* __restrict__ QC, const float* __restrict__ BE,
    float* __restrict__ out)
{
    const int lane = threadIdx.x & 63;
    const int wib  = threadIdx.x >> 6;
    const int W    = blockIdx.x * 4 + wib;       // 0..4095
    const int wg   = W & 255;                    // b-octet
    const int c    = W >> 8;                     // chunk
    const int sl   = lane & 7;
    const int g    = lane >> 3;
    const int b    = wg * 8 + g;
    const int t0   = c * LCH;

    f32x2 p[7];
    #pragma unroll
    for (int k = 0; k < 7; ++k)
        p[k] = (f32x2){ (float)(sl + 16 * k)     * (1.f / 99.f),
                        (float)(sl + 16 * k + 8) * (1.f / 99.f) };
    const f32x2 clA = { 1e-30f, 1e-30f };
    const f32x2 cl6 = { (sl < 4) ? 1e-30f : 0.f, 0.f };   // pair 6: i=96..111

    // chunk-entry beliefs
    const float* ebase = BE + (size_t)c * (BB * NG) + (size_t)b * NG;
    f32x2 be[7];
    #pragma unroll
    for (int k = 0; k < 6; ++k)
        be[k] = (f32x2){ ebase[sl + 16 * k], ebase[sl + 16 * k + 8] };
    be[6] = (f32x2){ (sl < 4) ? ebase[sl + 96] : 0.f, 0.f };

    const char* QCb = (const char*)QC;
    char* outb = (char*)out;
    unsigned off  = ((unsigned)t0 * BB + (unsigned)b) * 16u;          // QC bytes
    unsigned soff = ((unsigned)t0 * (2 * BB) + 2 * (unsigned)b) * 4u; // out bytes

    float4 pre[JJ];
    #pragma unroll
    for (int j = 0; j < JJ; ++j)
        pre[j] = *(const float4*)(QCb + (off + (unsigned)j * (BB * 16u)));
    off += JJ * (BB * 16u);

    for (int tt = 0; tt < LCH; tt += JJ) {
        float S[JJ], Sp[JJ], Zv[JJ], Wv[JJ];
        #pragma unroll
        for (int j = 0; j < JJ; ++j) {
            float4 q = pre[j];
            pre[j] = *(const float4*)(QCb + (off + (unsigned)j * (BB * 16u)));
            f32x2 qx = { q.x, q.x }, qy = { q.y, q.y };
            #pragma unroll
            for (int k = 0; k < 7; ++k) {
                f32x2 u = qy * p[k] + qx;
                be[k] = __builtin_elementwise_max(be[k] * u,
                                                  (k == 6) ? cl6 : clA);
            }
            f32x2 sA = ((be[0] + be[1]) + (be[2] + be[3]))
                     + ((be[4] + be[5]) + be[6]);
            S[j] = sA.x + sA.y;
            f32x2 a1 = be[0] * p[0], a2 = be[1] * p[1];
            a1 = be[2] * p[2] + a1;  a2 = be[3] * p[3] + a2;
            a1 = be[4] * p[4] + a1;  a2 = be[5] * p[5] + a2;
            a1 = be[6] * p[6] + a1;
            f32x2 aa = a1 + a2;
            Sp[j] = aa.x + aa.y;
            Zv[j] = q.z;
            Wv[j] = q.w;
        }
        off += JJ * (BB * 16u);
        #pragma unroll
        for (int j = 0; j < JJ; ++j) {
            float st = red8(S[j]);
            float sr = red8(Sp[j]);
            float E  = sr * __builtin_amdgcn_rcpf(st);
            float A  = Wv[j] - Zv[j];
            float l0 = fmaf(A, E, Zv[j]);
            float l1 = fmaf(-A, E, Wv[j]);
            if (sl == 0)   // 8 lanes store 8B each; octet is 64B contiguous
                *(float2*)(outb + (soff + (unsigned)j * (2 * BB * 4u))) =
                    make_float2(l0, l1);
        }
        soff += JJ * (2 * BB * 4u);
    }

    if (c == NCH - 1) {   // final belief carry: out[T*B*2 + b*100 + i]
        float* bel = out + (size_t)TT * BB * 2 + (size_t)b * NG;
        #pragma unroll
        for (int k = 0; k < 6; ++k) {
            bel[sl + 16 * k]     = be[k].x;
            bel[sl + 16 * k + 8] = be[k].y;
        }
        if (sl < 4) bel[sl + 96] = be[6].x;
    }
}

extern "C" void kernel_launch(void* const* d_in, const int* in_sizes, int n_in,
                              void* d_out, int out_size, void* d_ws, size_t ws_size,
                              hipStream_t stream)
{
    const float* x         = (const float*)d_in[0];
    const float* beta_raw  = (const float*)d_in[1];
    const float* sigma_raw = (const float*)d_in[2];
    float* out = (float*)d_out;

    // workspace: QC (32 MiB) | UC (26.2 MB) | BE (13.1 MB)  ~= 72 MB
    char* ws = (char*)d_ws;
    float4* QC = (float4*)ws;
    float2* UC = (float2*)(ws + (size_t)TT * BB * 16);
    float*  BE = (float*) (ws + (size_t)TT * BB * 16 + (size_t)NCH * BB * NG * 8);

    phase1_kernel<<<(TT * BB) / 256, 256, 0, stream>>>(x, beta_raw, sigma_raw, QC);
    phaseA_kernel<<<(BB / 2) * NCH / 4, 256, 0, stream>>>(QC, UC);
    phaseB_kernel<<<(BB * NG) / 256, 256, 0, stream>>>(UC, BE);
    phaseC_kernel<<<(BB / 8) * NCH / 4, 256, 0, stream>>>(QC, BE, out);
}

// Round 8
// 192.650 us; speedup vs baseline: 2.2044x; 1.1313x over previous
//
#include <hip/hip_runtime.h>
#include <math.h>

#define TT  1024
#define BB  2048
#define FF  11
#define PP  256
#define NG  100
#define NCH 16           // chunks over T
#define LCH (TT / NCH)   // 64 steps per chunk
#define JJ  4            // phaseC unroll / prefetch depth

typedef float f32x2 __attribute__((ext_vector_type(2)));

__device__ __forceinline__ float nz(float v) { return (v != v) ? 0.f : v; }

// Branch-free erf, Abramowitz-Stegun 7.1.26, |err| <= 1.5e-7 (abs).
__device__ __forceinline__ float erf_fast(float x) {
    float ax = fabsf(x);
    float t  = __builtin_amdgcn_rcpf(fmaf(0.3275911f, ax, 1.f));
    float y  = fmaf(fmaf(fmaf(fmaf(1.061405429f, t, -1.453152027f), t,
                              1.421413741f), t, -0.284496736f), t, 0.254829592f);
    y *= t;
    float r = fmaf(-y, __expf(-ax * ax), 1.f);
    return copysignf(r, x);
}

// q coefficients for one (t,b) record. Returns (q0, q1, B0=beta*pi1n, B1=beta*pi0n).
__device__ __forceinline__ float4 q_from_rec(
    float a0, float a1, float r0, float r1, float cdc, float cdn,
    float beta, float inv_s)
{
    float u = 0.5f * (1.f + erf_fast((0.0f  - cdc) * inv_s));
    float v = 0.5f * (1.f + erf_fast((-0.1f - cdc) * inv_s));
    float w = 0.5f * (1.f + erf_fast((0.1f  - cdc) * inv_s));
    float inv = 1.f / fmaxf(w - v, 1e-10f);
    float pi0 = fminf(fmaxf((u - v) * inv, 0.f), 1.f);
    float pi1 = fminf(fmaxf((w - u) * inv, 0.f), 1.f);

    u = 0.5f * (1.f + erf_fast((0.0f  - cdn) * inv_s));
    v = 0.5f * (1.f + erf_fast((-0.1f - cdn) * inv_s));
    w = 0.5f * (1.f + erf_fast((0.1f  - cdn) * inv_s));
    inv = 1.f / fmaxf(w - v, 1e-10f);
    float pi0n = fminf(fmaxf((u - v) * inv, 0.f), 1.f);
    float pi1n = fminf(fmaxf((w - u) * inv, 0.f), 1.f);

    float rs = r0 * a0 + r1 * a1;
    float r  = (a0 >= a1) ? rs : 1.f - rs;      // argmax tie -> index 0
    float q0 = pi1 * r + pi0 * (1.f - r);
    float q1 = (2.f * r - 1.f) * (pi0 - pi1);
    if (!((a0 + a1) > 0.f)) { q0 = 1.f; q1 = 0.f; }
    return make_float4(q0, q1, beta * pi1n, beta * pi0n);
}

// be' = max(be*u, 1e-30) composes over a chunk as be_out = max(be_in*U, C):
// U = prod(u), C = max-scan of floor. Exact semantics, scan-able over T.

// ---------------- Phase Aq: fused coeff-compute + per-chunk (U,C) ------------
// 8 lanes per b, 8 b per wave; wave W: b-octet wg = W & 255, chunk c = W >> 8.
// Per 8-step block, lane (g, sl) computes the q-record for (t0+tt+sl, b_g),
// stores it to QC (for phaseC), and the group consumes q via __shfl broadcast.
// Lane owns 7 slot-pairs {sl+16k, sl+16k+8}; grid points >=100 are hard zeros.
__global__ __launch_bounds__(256) void phaseAq_kernel(
    const float* __restrict__ x, const float* __restrict__ beta_raw,
    const float* __restrict__ sigma_raw, float4* __restrict__ QC,
    float2* __restrict__ UC)
{
    const int lane = threadIdx.x & 63;
    const int wib  = threadIdx.x >> 6;
    const int W    = blockIdx.x * 4 + wib;       // 0..4095
    const int wg   = W & 255;                    // b-octet
    const int c    = W >> 8;                     // chunk
    const int sl   = lane & 7;
    const int g    = lane >> 3;
    const int b    = wg * 8 + g;
    const int t0   = c * LCH;

    // per-b participant params (computed once; 8 lanes of a group redundant)
    int pid = (int)nz(x[(size_t)b * FF + 10]);
    pid = pid < 0 ? 0 : (pid > PP - 1 ? PP - 1 : pid);
    float br = beta_raw[pid];
    float sr = sigma_raw[pid];
    float sp   = fmaxf(br, 0.f) + log1pf(__expf(-fabsf(br)));
    float beta = fminf(fmaxf(sp + 1.f, 1.f), 25.f);
    float sig  = fminf(fmaxf(__builtin_amdgcn_rcpf(1.f + __expf(-sr)) * 0.09f + 0.01f,
                             0.01f), 0.1f);
    float inv_s = 1.f / (sig * 1.41421356237309505f);

    f32x2 p[7];
    #pragma unroll
    for (int k = 0; k < 7; ++k)
        p[k] = (f32x2){ (float)(sl + 16 * k)     * (1.f / 99.f),
                        (float)(sl + 16 * k + 8) * (1.f / 99.f) };
    const f32x2 clA = { 1e-30f, 1e-30f };
    const f32x2 cl6 = { (sl < 4) ? 1e-30f : 0.f, 0.f };   // pair 6: i=96..111

    f32x2 U[7], C[7];
    #pragma unroll
    for (int k = 0; k < 7; ++k) { U[k] = (f32x2){1.f, 1.f}; C[k] = (f32x2){0.f, 0.f}; }

    // first record for this lane: t = t0 + sl
    const float* rp = x + ((size_t)(t0 + sl) * BB + b) * FF;
    float4 qc;
    {
        float a0 = nz(rp[0]), a1 = nz(rp[1]), r0 = nz(rp[2]),
              r1 = nz(rp[3]), dc = nz(rp[4]), dn = nz(rp[5]);
        qc = q_from_rec(a0, a1, r0, r1, dc, dn, beta, inv_s);
        QC[(size_t)(t0 + sl) * BB + b] = qc;
    }

    for (int tt = 0; tt < LCH; tt += 8) {
        const bool have = (tt + 8) < LCH;
        float na0, na1, nr0, nr1, ndc, ndn;
        if (have) {   // uniform branch; prefetch next block's record
            const float* np = x + ((size_t)(t0 + tt + 8 + sl) * BB + b) * FF;
            na0 = nz(np[0]); na1 = nz(np[1]); nr0 = nz(np[2]);
            nr1 = nz(np[3]); ndc = nz(np[4]); ndn = nz(np[5]);
        }
        // broadcast current block's q to the 8-lane group (2 bpermute/step)
        float q0b[8], q1b[8];
        #pragma unroll
        for (int j = 0; j < 8; ++j) {
            q0b[j] = __shfl(qc.x, (lane & 56) + j);
            q1b[j] = __shfl(qc.y, (lane & 56) + j);
        }
        #pragma unroll
        for (int j = 0; j < 8; ++j) {
            f32x2 qx = { q0b[j], q0b[j] }, qy = { q1b[j], q1b[j] };
            #pragma unroll
            for (int k = 0; k < 7; ++k) {
                f32x2 u = qy * p[k] + qx;            // v_pk_fma_f32
                U[k] *= u;
                C[k] = __builtin_elementwise_max(C[k] * u, (k == 6) ? cl6 : clA);
            }
        }
        if (have) {   // compute + store next block's record
            qc = q_from_rec(na0, na1, nr0, nr1, ndc, ndn, beta, inv_s);
            QC[(size_t)(t0 + tt + 8 + sl) * BB + b] = qc;
        }
    }

    // UC[(c*BB + b)*100 + i] = (U, C) for live grid points
    float2* dst = UC + ((size_t)c * BB + b) * NG;
    #pragma unroll
    for (int k = 0; k < 6; ++k) {
        dst[sl + 16 * k]     = make_float2(U[k].x, C[k].x);
        dst[sl + 16 * k + 8] = make_float2(U[k].y, C[k].y);
    }
    if (sl < 4) dst[sl + 96] = make_float2(U[6].x, C[6].x);
}

// ---------------- Phase B: 16-step scan over chunks per (b,i) ----------------
__global__ __launch_bounds__(256) void phaseB_kernel(
    const float2* __restrict__ UC, float* __restrict__ BE)
{
    const int flat = blockIdx.x * 256 + threadIdx.x;   // flat = b*100 + i
    float be = 1.f;
    #pragma unroll
    for (int c = 0; c < NCH; ++c) {
        BE[(size_t)c * (BB * NG) + flat] = be;
        float2 uc = UC[(size_t)c * (BB * NG) + flat];
        be = fmaxf(be * uc.x, uc.y);
    }
}

// ---------------- Phase C: parallel chunk re-walk, logits + carry ------------
// 8 lanes per b, 8 b per wave; same slot-pair layout as phaseAq.
__global__ __launch_bounds__(256) void phaseC_kernel(
    const float4* __restrict__ QC, const float* __restrict__ BE,
    float* __restrict__ out)
{
    const int lane = threadIdx.x & 63;
    const int wib  = threadIdx.x >> 6;
    const int W    = blockIdx.x * 4 + wib;       // 0..4095
    const int wg   = W & 255;                    // b-octet
    const int c    = W >> 8;                     // chunk
    const int sl   = lane & 7;
    const int g    = lane >> 3;
    const int b    = wg * 8 + g;
    const int t0   = c * LCH;

    f32x2 p[7];
    #pragma unroll
    for (int k = 0; k < 7; ++k)
        p[k] = (f32x2){ (float)(sl + 16 * k)     * (1.f / 99.f),
                        (float)(sl + 16 * k + 8) * (1.f / 99.f) };
    const f32x2 clA = { 1e-30f, 1e-30f };
    const f32x2 cl6 = { (sl < 4) ? 1e-30f : 0.f, 0.f };   // pair 6: i=96..111

    // chunk-entry beliefs
    const float* ebase = BE + (size_t)c * (BB * NG) + (size_t)b * NG;
    f32x2 be[7];
    #pragma unroll
    for (int k = 0; k < 6; ++k)
        be[k] = (f32x2){ ebase[sl + 16 * k], ebase[sl + 16 * k + 8] };
    be[6] = (f32x2){ (sl < 4) ? ebase[sl + 96] : 0.f, 0.f };

    const char* QCb = (const char*)QC;
    char* outb = (char*)out;
    unsigned off  = ((unsigned)t0 * BB + (unsigned)b) * 16u;          // QC bytes
    unsigned soff = ((unsigned)t0 * (2 * BB) + 2 * (unsigned)b) * 4u; // out bytes

    float4 pre[JJ];
    #pragma unroll
    for (int j = 0; j < JJ; ++j)
        pre[j] = *(const float4*)(QCb + (off + (unsigned)j * (BB * 16u)));
    off += JJ * (BB * 16u);

    for (int tt = 0; tt < LCH; tt += JJ) {
        float S[JJ], Sp[JJ], Zv[JJ], Wv[JJ];
        #pragma unroll
        for (int j = 0; j < JJ; ++j) {
            float4 q = pre[j];
            // overrun prefetch (last iter) lands in UC region: never consumed
            pre[j] = *(const float4*)(QCb + (off + (unsigned)j * (BB * 16u)));
            f32x2 qx = { q.x, q.x }, qy = { q.y, q.y };
            #pragma unroll
            for (int k = 0; k < 7; ++k) {
                f32x2 u = qy * p[k] + qx;
                be[k] = __builtin_elementwise_max(be[k] * u,
                                                  (k == 6) ? cl6 : clA);
            }
            f32x2 sA = ((be[0] + be[1]) + (be[2] + be[3]))
                     + ((be[4] + be[5]) + be[6]);
            S[j] = sA.x + sA.y;
            f32x2 a1 = be[0] * p[0], a2 = be[1] * p[1];
            a1 = be[2] * p[2] + a1;  a2 = be[3] * p[3] + a2;
            a1 = be[4] * p[4] + a1;  a2 = be[5] * p[5] + a2;
            a1 = be[6] * p[6] + a1;
            f32x2 aa = a1 + a2;
            Sp[j] = aa.x + aa.y;
            Zv[j] = q.z;
            Wv[j] = q.w;
        }
        off += JJ * (BB * 16u);
        #pragma unroll
        for (int j = 0; j < JJ; ++j) {
            // 8-lane butterfly sum (pure VALU DPP)
            float st = S[j], sr = Sp[j];
            {
                int t;
                t = __builtin_amdgcn_update_dpp(0, __float_as_int(st), 0xB1, 0xF, 0xF, true);
                st += __int_as_float(t);
                t = __builtin_amdgcn_update_dpp(0, __float_as_int(sr), 0xB1, 0xF, 0xF, true);
                sr += __int_as_float(t);
                t = __builtin_amdgcn_update_dpp(0, __float_as_int(st), 0x4E, 0xF, 0xF, true);
                st += __int_as_float(t);
                t = __builtin_amdgcn_update_dpp(0, __float_as_int(sr), 0x4E, 0xF, 0xF, true);
                sr += __int_as_float(t);
                t = __builtin_amdgcn_update_dpp(0, __float_as_int(st), 0x141, 0xF, 0xF, true);
                st += __int_as_float(t);
                t = __builtin_amdgcn_update_dpp(0, __float_as_int(sr), 0x141, 0xF, 0xF, true);
                sr += __int_as_float(t);
            }
            float E  = sr * __builtin_amdgcn_rcpf(st);
            float A  = Wv[j] - Zv[j];
            float l0 = fmaf(A, E, Zv[j]);
            float l1 = fmaf(-A, E, Wv[j]);
            if (sl == 0)   // 8 lanes store 8B each; octet is 64B contiguous
                *(float2*)(outb + (soff + (unsigned)j * (2 * BB * 4u))) =
                    make_float2(l0, l1);
        }
        soff += JJ * (2 * BB * 4u);
    }

    if (c == NCH - 1) {   // final belief carry: out[T*B*2 + b*100 + i]
        float* bel = out + (size_t)TT * BB * 2 + (size_t)b * NG;
        #pragma unroll
        for (int k = 0; k < 6; ++k) {
            bel[sl + 16 * k]     = be[k].x;
            bel[sl + 16 * k + 8] = be[k].y;
        }
        if (sl < 4) bel[sl + 96] = be[6].x;
    }
}

extern "C" void kernel_launch(void* const* d_in, const int* in_sizes, int n_in,
                              void* d_out, int out_size, void* d_ws, size_t ws_size,
                              hipStream_t stream)
{
    const float* x         = (const float*)d_in[0];
    const float* beta_raw  = (const float*)d_in[1];
    const float* sigma_raw = (const float*)d_in[2];
    float* out = (float*)d_out;

    // workspace: QC (32 MiB) | UC (26.2 MB) | BE (13.1 MB)  ~= 72 MB
    char* ws = (char*)d_ws;
    float4* QC = (float4*)ws;
    float2* UC = (float2*)(ws + (size_t)TT * BB * 16);
    float*  BE = (float*) (ws + (size_t)TT * BB * 16 + (size_t)NCH * BB * NG * 8);

    phaseAq_kernel<<<(BB / 8) * NCH / 4, 256, 0, stream>>>(x, beta_raw, sigma_raw, QC, UC);
    phaseB_kernel<<<(BB * NG) / 256, 256, 0, stream>>>(UC, BE);
    phaseC_kernel<<<(BB / 8) * NCH / 4, 256, 0, stream>>>(QC, BE, out);
}